// Round 13
// baseline (77.435 us; speedup 1.0000x reference)
//
#include <hip/hip_runtime.h>
#include <math.h>

// (B,H,N,D) = (2,16,4096,128), fp32 in/out.
static constexpr int kN   = 4096;
static constexpr int kD   = 128;
static constexpr int kBH  = 32;        // B*H channel groups
static constexpr int kD4  = 32;        // float4 (d-quads) per row

typedef float v4f __attribute__((ext_vector_type(4)));

__device__ __forceinline__ float fast_sigmoid(float x) {
    return __builtin_amdgcn_rcpf(1.0f + __expf(-x));
}

// round-to-nearest-even fp32 -> bf16
__device__ __forceinline__ unsigned short f2b(float x) {
    union { float f; unsigned u; } cv; cv.f = x;
    unsigned u = cv.u;
    u += 0x7fffu + ((u >> 16) & 1u);
    return (unsigned short)(u >> 16);
}
__device__ __forceinline__ float b2f(unsigned short b) {
    union { unsigned u; float f; } cv; cv.u = ((unsigned)b) << 16;
    return cv.f;
}

// ===========================================================================
// Structure (3 kernels):
//   p1:   C=1024 chunks (T=4), 4096 blocks (max TLP — the proven lever).
//         bf16 within-chunk scan -> wscan (temporal: stays in L2/L3 for emit);
//         fp32 macro totals (macro = 8 chunks = 32 steps) -> M. NT input loads.
//   p2b:  exclusive scan of 128 macro totals per (bh,d) channel (in place).
//   p3:   2048 blocks; thread = 8 contiguous timesteps = 2 chunks. Chunk
//         prefixes from 16 bf16 chunk totals (LDS) + fp32 half-macro prefix;
//         single NT write of out.
// ===========================================================================
static constexpr int C1 = 1024;
static constexpr int T1 = kN / C1;                  // 4
static constexpr int M1 = 128;                      // macros per bh
static constexpr int NBLK1 = kBH * M1;              // 4096 (p1 grid)
static constexpr int NBLK3 = kBH * 64;              // 2048 (emit grid)

// Pass 1: gated within-chunk inclusive scan.
__global__ __launch_bounds__(256, 2) void gla1_scan(
    const float4* __restrict__ q, const float4* __restrict__ k,
    const float4* __restrict__ v, const float4* __restrict__ g,
    ushort4* __restrict__ wscan, float4* __restrict__ macros)
{
    __shared__ float4 lds[8][kD4];         // 4 KB: per-chunk totals

    const int lane = threadIdx.x & (kD4 - 1);
    const int grp  = threadIdx.x >> 5;     // chunk-within-macro 0..7
    const int bh   = blockIdx.x >> 7;      // M1=128 blocks per bh
    const int m    = blockIdx.x & (M1 - 1);
    const int c    = m * 8 + grp;          // chunk index 0..1023

    const size_t base = ((size_t)bh * kN + (size_t)c * T1) * kD4 + lane;

    float4 acc = make_float4(0.f, 0.f, 0.f, 0.f);
#pragma unroll
    for (int t = 0; t < T1; ++t) {
        const size_t idx = base + (size_t)t * kD4;
        const v4f q4 = __builtin_nontemporal_load((const v4f*)&q[idx]);
        const v4f k4 = __builtin_nontemporal_load((const v4f*)&k[idx]);
        const v4f g4 = __builtin_nontemporal_load((const v4f*)&g[idx]);
        const v4f v4 = __builtin_nontemporal_load((const v4f*)&v[idx]);
        acc.x += v4.x * fast_sigmoid(q4.x * k4.x + g4.x);
        acc.y += v4.y * fast_sigmoid(q4.y * k4.y + g4.y);
        acc.z += v4.z * fast_sigmoid(q4.z * k4.z + g4.z);
        acc.w += v4.w * fast_sigmoid(q4.w * k4.w + g4.w);
        ushort4 p;
        p.x = f2b(acc.x); p.y = f2b(acc.y); p.z = f2b(acc.z); p.w = f2b(acc.w);
        wscan[idx] = p;
    }
    lds[grp][lane] = acc;
    __syncthreads();

    // Macro total: this block IS macro (bh, m).
    if (threadIdx.x < kD4) {
        float4 s = lds[0][threadIdx.x];
#pragma unroll
        for (int g2 = 1; g2 < 8; ++g2) {
            const float4 a = lds[g2][threadIdx.x];
            s.x += a.x; s.y += a.y; s.z += a.z; s.w += a.w;
        }
        macros[(size_t)blockIdx.x * kD4 + threadIdx.x] = s;  // M[bh][m][dq]
    }
}

// Pass 2b: in-place exclusive scan over M1 macro totals per (bh,d) channel.
__global__ void gla1_macroscan(float* __restrict__ M)
{
    const int bh = blockIdx.x;              // 32 blocks
    const int d  = threadIdx.x;             // 0..127
    const size_t base = (size_t)bh * M1 * kD + d;
    float run = 0.f;
    for (int m0 = 0; m0 < M1; m0 += 16) {
        float tv[16];
#pragma unroll
        for (int j = 0; j < 16; ++j)
            tv[j] = M[base + (size_t)(m0 + j) * kD];
#pragma unroll
        for (int j = 0; j < 16; ++j) {
            const float t = tv[j];
            M[base + (size_t)(m0 + j) * kD] = run;
            run += t;
        }
    }
}

// Pass 3: 2048 blocks; block covers 64 timesteps = 16 chunks (2 p1-macros).
// Thread = 8 contiguous timesteps (chunks 2*grp, 2*grp+1 of the block).
__global__ __launch_bounds__(256) void gla2_emit(
    const ushort4* __restrict__ wscan, const float4* __restrict__ macros,
    float4* __restrict__ out)
{
    __shared__ float4 lds[16][kD4];        // 8 KB: 16 chunk totals

    const int lane = threadIdx.x & (kD4 - 1);
    const int grp  = threadIdx.x >> 5;     // 0..7
    const int bh   = blockIdx.x >> 6;      // 64 blocks per bh
    const int bm   = blockIdx.x & 63;      // 64-step super-tile index

    const size_t base =
        ((size_t)bh * kN + (size_t)bm * 64 + (size_t)grp * 8) * kD4 + lane;

    ushort4 p[8];
#pragma unroll
    for (int t = 0; t < 8; ++t)
        p[t] = wscan[base + (size_t)t * kD4];

    // bf16 chunk totals (last scan element of each T=4 chunk).
    const float4 tot0 = make_float4(b2f(p[3].x), b2f(p[3].y),
                                    b2f(p[3].z), b2f(p[3].w));
    const float4 tot1 = make_float4(b2f(p[7].x), b2f(p[7].y),
                                    b2f(p[7].z), b2f(p[7].w));
    const int idx0 = 2 * grp;
    lds[idx0][lane]     = tot0;
    lds[idx0 + 1][lane] = tot1;

    // fp32 half-macro prefix: macro = bm*2 + (grp>=4).
    const int half = (grp >= 4) ? 1 : 0;
    float4 pre =
        macros[((size_t)bh * M1 + (size_t)bm * 2 + half) * kD4 + lane];
    __syncthreads();

    // Add preceding chunks' bf16 totals within this half-macro (<=7 adds).
    const int start = half * 8;
    for (int j = start; j < idx0; ++j) {
        const float4 a = lds[j][lane];
        pre.x += a.x; pre.y += a.y; pre.z += a.z; pre.w += a.w;
    }

#pragma unroll
    for (int t = 0; t < 4; ++t) {
        v4f o;
        o.x = b2f(p[t].x) + pre.x;
        o.y = b2f(p[t].y) + pre.y;
        o.z = b2f(p[t].z) + pre.z;
        o.w = b2f(p[t].w) + pre.w;
        __builtin_nontemporal_store(o, (v4f*)&out[base + (size_t)t * kD4]);
    }
    pre.x += tot0.x; pre.y += tot0.y; pre.z += tot0.z; pre.w += tot0.w;
#pragma unroll
    for (int t = 4; t < 8; ++t) {
        v4f o;
        o.x = b2f(p[t].x) + pre.x;
        o.y = b2f(p[t].y) + pre.y;
        o.z = b2f(p[t].z) + pre.z;
        o.w = b2f(p[t].w) + pre.w;
        __builtin_nontemporal_store(o, (v4f*)&out[base + (size_t)t * kD4]);
    }
}

// ===========================================================================
// Fallback path (proven round-1 code): C=128 or C=32, fp32 scan in out.
// ===========================================================================
template <int CC>
__global__ __launch_bounds__(256) void gla_pass1(
    const float4* __restrict__ q, const float4* __restrict__ k,
    const float4* __restrict__ v, const float4* __restrict__ g,
    float4* __restrict__ out, float4* __restrict__ sums)
{
    constexpr int TT = kN / CC;
    const int gtid = blockIdx.x * 256 + threadIdx.x;
    const int lane = gtid & (kD4 - 1);
    const int task = gtid >> 5;
    const int bh   = task / CC;
    const int c    = task & (CC - 1);
    size_t base = ((size_t)bh * kN + (size_t)c * TT) * kD4 + lane;
    float4 acc = make_float4(0.f, 0.f, 0.f, 0.f);
#pragma unroll 4
    for (int t = 0; t < TT; ++t) {
        const size_t idx = base + (size_t)t * kD4;
        const float4 q4 = q[idx], k4 = k[idx], g4 = g[idx], v4 = v[idx];
        acc.x += v4.x * fast_sigmoid(q4.x * k4.x + g4.x);
        acc.y += v4.y * fast_sigmoid(q4.y * k4.y + g4.y);
        acc.z += v4.z * fast_sigmoid(q4.z * k4.z + g4.z);
        acc.w += v4.w * fast_sigmoid(q4.w * k4.w + g4.w);
        out[idx] = acc;
    }
    sums[(size_t)task * kD4 + lane] = acc;
}

template <int CC>
__global__ void gla_pass2(float* __restrict__ sums)
{
    const int bh = blockIdx.x;
    const int d  = threadIdx.x;
    size_t base = (size_t)bh * CC * kD + d;
    float run = 0.f;
#pragma unroll
    for (int c2 = 0; c2 < CC; ++c2) {
        const size_t i = base + (size_t)c2 * kD;
        const float t = sums[i];
        sums[i] = run;
        run += t;
    }
}

template <int CC>
__global__ __launch_bounds__(256) void gla_pass3(
    float4* __restrict__ out, const float4* __restrict__ sums)
{
    constexpr int TT = kN / CC;
    const int gtid = blockIdx.x * 256 + threadIdx.x;
    const int lane = gtid & (kD4 - 1);
    const int nt   = gtid >> 5;
    const int bh   = nt / kN;
    const int t    = nt & (kN - 1);
    const int c    = t / TT;
    const float4 add = sums[((size_t)bh * CC + c) * kD4 + lane];
    float4 o = out[gtid];
    o.x += add.x; o.y += add.y; o.z += add.z; o.w += add.w;
    out[gtid] = o;
}

// ===========================================================================
extern "C" void kernel_launch(void* const* d_in, const int* in_sizes, int n_in,
                              void* d_out, int out_size, void* d_ws,
                              size_t ws_size, hipStream_t stream)
{
    const float4* q = (const float4*)d_in[0];
    const float4* k = (const float4*)d_in[1];
    const float4* v = (const float4*)d_in[2];
    const float4* g = (const float4*)d_in[3];
    float4* out = (float4*)d_out;

    // Primary ws layout: bf16 wscan | fp32 macro sums
    constexpr size_t kWscanBytes = (size_t)kBH * kN * kD4 * sizeof(ushort4); // 33.55 MB
    constexpr size_t kMacroBytes = (size_t)NBLK1 * kD4 * sizeof(float4);     //  2.10 MB
    constexpr size_t kNeed1 = kWscanBytes + kMacroBytes;

    if (ws_size >= kNeed1) {
        ushort4* wscan  = (ushort4*)d_ws;
        float4*  macros = (float4*)((char*)d_ws + kWscanBytes);
        gla1_scan<<<NBLK1, 256, 0, stream>>>(q, k, v, g, wscan, macros);
        gla1_macroscan<<<kBH, kD, 0, stream>>>((float*)macros);
        gla2_emit<<<NBLK3, 256, 0, stream>>>(wscan, macros, out);
    } else if (ws_size >= (size_t)kBH * 128 * kD * sizeof(float)) {
        constexpr int CC = 128;
        const int threads1 = kBH * CC * 32;
        gla_pass1<CC><<<threads1 / 256, 256, 0, stream>>>(q, k, v, g, out,
                                                          (float4*)d_ws);
        gla_pass2<CC><<<kBH, kD, 0, stream>>>((float*)d_ws);
        const int threads3 = kBH * kN * kD4;
        gla_pass3<CC><<<threads3 / 256, 256, 0, stream>>>(out,
                                                          (const float4*)d_ws);
    } else {
        constexpr int CC = 32;
        const int threads1 = kBH * CC * 32;
        gla_pass1<CC><<<threads1 / 256, 256, 0, stream>>>(q, k, v, g, out,
                                                          (float4*)d_ws);
        gla_pass2<CC><<<kBH, kD, 0, stream>>>((float*)d_ws);
        const int threads3 = kBH * kN * kD4;
        gla_pass3<CC><<<threads3 / 256, 256, 0, stream>>>(out,
                                                          (const float4*)d_ws);
    }
}

// Round 14
// 73.188 us; speedup vs baseline: 1.0580x; 1.0580x over previous
//
#include <hip/hip_runtime.h>
#include <math.h>

// (B,H,N,D) = (2,16,4096,128), fp32 in/out.
// ROUND-10 CONFIGURATION (measured optimum, 73.5 us):
//   - C=512 (T=8), p1 and emit BOTH on 2048-block grids with the SAME
//     blockIdx->data mapping (wscan writer and reader land on the same XCD
//     -> L2-local reads; rounds 12/13 broke this and lost ~7 us).
//   - NT input loads (read-once, don't evict wscan from L3).
//   - bf16 wscan staging (halves intermediate bytes vs fp32).
//   - No per-chunk sums array: emit reconstructs chunk prefixes from each
//     chunk's last bf16 element via LDS + fp32 macro prefix.
//   - Single NT write of out.
static constexpr int kN   = 4096;
static constexpr int kD   = 128;
static constexpr int kBH  = 32;        // B*H channel groups
static constexpr int kD4  = 32;        // float4 (d-quads) per row

typedef float v4f __attribute__((ext_vector_type(4)));

__device__ __forceinline__ float fast_sigmoid(float x) {
    return __builtin_amdgcn_rcpf(1.0f + __expf(-x));
}

// round-to-nearest-even fp32 -> bf16
__device__ __forceinline__ unsigned short f2b(float x) {
    union { float f; unsigned u; } cv; cv.f = x;
    unsigned u = cv.u;
    u += 0x7fffu + ((u >> 16) & 1u);
    return (unsigned short)(u >> 16);
}
__device__ __forceinline__ float b2f(unsigned short b) {
    union { unsigned u; float f; } cv; cv.u = ((unsigned)b) << 16;
    return cv.f;
}

static constexpr int C1 = 512;
static constexpr int T1 = kN / C1;                  // 8
static constexpr int M1 = 64;                       // macros per bh
static constexpr int NBLK = kBH * M1;               // 2048 blocks (p1 AND emit)

// Pass 1: gated within-chunk inclusive scan -> bf16 wscan; macro totals -> M.
__global__ __launch_bounds__(256) void gla1_scan(
    const float4* __restrict__ q, const float4* __restrict__ k,
    const float4* __restrict__ v, const float4* __restrict__ g,
    ushort4* __restrict__ wscan, float4* __restrict__ macros)
{
    __shared__ float4 lds[8][kD4];         // 4 KB: per-chunk totals

    const int gtid = blockIdx.x * 256 + threadIdx.x;
    const int lane = gtid & (kD4 - 1);
    const int task = gtid >> 5;            // bh*C1 + c
    const int bh   = task >> 9;            // /512
    const int c    = task & (C1 - 1);
    const int grp  = threadIdx.x >> 5;     // chunk-within-macro 0..7

    const size_t base = ((size_t)bh * kN + (size_t)c * T1) * kD4 + lane;

    float4 acc = make_float4(0.f, 0.f, 0.f, 0.f);
#pragma unroll
    for (int t = 0; t < T1; ++t) {
        const size_t idx = base + (size_t)t * kD4;
        const v4f q4 = __builtin_nontemporal_load((const v4f*)&q[idx]);
        const v4f k4 = __builtin_nontemporal_load((const v4f*)&k[idx]);
        const v4f g4 = __builtin_nontemporal_load((const v4f*)&g[idx]);
        const v4f v4 = __builtin_nontemporal_load((const v4f*)&v[idx]);
        acc.x += v4.x * fast_sigmoid(q4.x * k4.x + g4.x);
        acc.y += v4.y * fast_sigmoid(q4.y * k4.y + g4.y);
        acc.z += v4.z * fast_sigmoid(q4.z * k4.z + g4.z);
        acc.w += v4.w * fast_sigmoid(q4.w * k4.w + g4.w);
        ushort4 p;
        p.x = f2b(acc.x); p.y = f2b(acc.y); p.z = f2b(acc.z); p.w = f2b(acc.w);
        wscan[idx] = p;
    }
    lds[grp][lane] = acc;
    __syncthreads();

    // Macro total: this block IS macro (bh, m = blockIdx & 63).
    if (threadIdx.x < kD4) {
        float4 s = lds[0][threadIdx.x];
#pragma unroll
        for (int g2 = 1; g2 < 8; ++g2) {
            const float4 a = lds[g2][threadIdx.x];
            s.x += a.x; s.y += a.y; s.z += a.z; s.w += a.w;
        }
        macros[(size_t)blockIdx.x * kD4 + threadIdx.x] = s;  // M[bh][m][dq]
    }
}

// Pass 2b: in-place exclusive scan over M1 macro totals per (bh,d) channel.
__global__ void gla1_macroscan(float* __restrict__ M)
{
    const int bh = blockIdx.x;              // 32 blocks
    const int d  = threadIdx.x;             // 0..127
    const size_t base = (size_t)bh * M1 * kD + d;
    float run = 0.f;
    for (int m0 = 0; m0 < M1; m0 += 16) {
        float tv[16];
#pragma unroll
        for (int j = 0; j < 16; ++j)
            tv[j] = M[base + (size_t)(m0 + j) * kD];
#pragma unroll
        for (int j = 0; j < 16; ++j) {
            const float t = tv[j];
            M[base + (size_t)(m0 + j) * kD] = run;
            run += t;
        }
    }
}

// Pass 3: block = macro (same mapping as p1 -> same-XCD wscan reads).
// Chunk prefix = fp32 macro prefix + preceding chunks' last bf16 elements
// (LDS exchange). One NT write of out.
__global__ __launch_bounds__(256) void gla2_emit(
    const ushort4* __restrict__ wscan, const float4* __restrict__ macros,
    float4* __restrict__ out)
{
    __shared__ float4 lds[8][kD4];         // 4 KB: per-chunk bf16 totals

    const int gtid = blockIdx.x * 256 + threadIdx.x;
    const int lane = gtid & (kD4 - 1);
    const int task = gtid >> 5;            // bh*C1 + c (same mapping as p1)
    const int bh   = task >> 9;
    const int c    = task & (C1 - 1);
    const int grp  = threadIdx.x >> 5;

    const size_t base = ((size_t)bh * kN + (size_t)c * T1) * kD4 + lane;

    ushort4 p[T1];
#pragma unroll
    for (int t = 0; t < T1; ++t)
        p[t] = wscan[base + (size_t)t * kD4];

    // This chunk's (bf16-rounded) total = last within-chunk scan element.
    const float4 tot = make_float4(b2f(p[T1-1].x), b2f(p[T1-1].y),
                                   b2f(p[T1-1].z), b2f(p[T1-1].w));
    lds[grp][lane] = tot;

    // Macro prefix (exclusive, fp32).
    float4 pre = macros[(size_t)blockIdx.x * kD4 + lane];
    __syncthreads();

    // Add preceding chunks' totals within this macro.
    for (int g2 = 0; g2 < grp; ++g2) {
        const float4 a = lds[g2][lane];
        pre.x += a.x; pre.y += a.y; pre.z += a.z; pre.w += a.w;
    }

#pragma unroll
    for (int t = 0; t < T1; ++t) {
        v4f o;
        o.x = b2f(p[t].x) + pre.x;
        o.y = b2f(p[t].y) + pre.y;
        o.z = b2f(p[t].z) + pre.z;
        o.w = b2f(p[t].w) + pre.w;
        __builtin_nontemporal_store(o, (v4f*)&out[base + (size_t)t * kD4]);
    }
}

// ===========================================================================
// Fallback path (proven round-1 code): C=128 or C=32, fp32 scan in out.
// ===========================================================================
template <int CC>
__global__ __launch_bounds__(256) void gla_pass1(
    const float4* __restrict__ q, const float4* __restrict__ k,
    const float4* __restrict__ v, const float4* __restrict__ g,
    float4* __restrict__ out, float4* __restrict__ sums)
{
    constexpr int TT = kN / CC;
    const int gtid = blockIdx.x * 256 + threadIdx.x;
    const int lane = gtid & (kD4 - 1);
    const int task = gtid >> 5;
    const int bh   = task / CC;
    const int c    = task & (CC - 1);
    size_t base = ((size_t)bh * kN + (size_t)c * TT) * kD4 + lane;
    float4 acc = make_float4(0.f, 0.f, 0.f, 0.f);
#pragma unroll 4
    for (int t = 0; t < TT; ++t) {
        const size_t idx = base + (size_t)t * kD4;
        const float4 q4 = q[idx], k4 = k[idx], g4 = g[idx], v4 = v[idx];
        acc.x += v4.x * fast_sigmoid(q4.x * k4.x + g4.x);
        acc.y += v4.y * fast_sigmoid(q4.y * k4.y + g4.y);
        acc.z += v4.z * fast_sigmoid(q4.z * k4.z + g4.z);
        acc.w += v4.w * fast_sigmoid(q4.w * k4.w + g4.w);
        out[idx] = acc;
    }
    sums[(size_t)task * kD4 + lane] = acc;
}

template <int CC>
__global__ void gla_pass2(float* __restrict__ sums)
{
    const int bh = blockIdx.x;
    const int d  = threadIdx.x;
    size_t base = (size_t)bh * CC * kD + d;
    float run = 0.f;
#pragma unroll
    for (int c2 = 0; c2 < CC; ++c2) {
        const size_t i = base + (size_t)c2 * kD;
        const float t = sums[i];
        sums[i] = run;
        run += t;
    }
}

template <int CC>
__global__ __launch_bounds__(256) void gla_pass3(
    float4* __restrict__ out, const float4* __restrict__ sums)
{
    constexpr int TT = kN / CC;
    const int gtid = blockIdx.x * 256 + threadIdx.x;
    const int lane = gtid & (kD4 - 1);
    const int nt   = gtid >> 5;
    const int bh   = nt / kN;
    const int t    = nt & (kN - 1);
    const int c    = t / TT;
    const float4 add = sums[((size_t)bh * CC + c) * kD4 + lane];
    float4 o = out[gtid];
    o.x += add.x; o.y += add.y; o.z += add.z; o.w += add.w;
    out[gtid] = o;
}

// ===========================================================================
extern "C" void kernel_launch(void* const* d_in, const int* in_sizes, int n_in,
                              void* d_out, int out_size, void* d_ws,
                              size_t ws_size, hipStream_t stream)
{
    const float4* q = (const float4*)d_in[0];
    const float4* k = (const float4*)d_in[1];
    const float4* v = (const float4*)d_in[2];
    const float4* g = (const float4*)d_in[3];
    float4* out = (float4*)d_out;

    // Primary ws layout: bf16 wscan | fp32 macro sums
    constexpr size_t kWscanBytes = (size_t)kBH * kN * kD4 * sizeof(ushort4); // 33.55 MB
    constexpr size_t kMacroBytes = (size_t)NBLK * kD4 * sizeof(float4);      //  1.05 MB
    constexpr size_t kNeed1 = kWscanBytes + kMacroBytes;

    if (ws_size >= kNeed1) {
        ushort4* wscan  = (ushort4*)d_ws;
        float4*  macros = (float4*)((char*)d_ws + kWscanBytes);
        gla1_scan<<<NBLK, 256, 0, stream>>>(q, k, v, g, wscan, macros);
        gla1_macroscan<<<kBH, kD, 0, stream>>>((float*)macros);
        gla2_emit<<<NBLK, 256, 0, stream>>>(wscan, macros, out);
    } else if (ws_size >= (size_t)kBH * 128 * kD * sizeof(float)) {
        constexpr int CC = 128;
        const int threads1 = kBH * CC * 32;
        gla_pass1<CC><<<threads1 / 256, 256, 0, stream>>>(q, k, v, g, out,
                                                          (float4*)d_ws);
        gla_pass2<CC><<<kBH, kD, 0, stream>>>((float*)d_ws);
        const int threads3 = kBH * kN * kD4;
        gla_pass3<CC><<<threads3 / 256, 256, 0, stream>>>(out,
                                                          (const float4*)d_ws);
    } else {
        constexpr int CC = 32;
        const int threads1 = kBH * CC * 32;
        gla_pass1<CC><<<threads1 / 256, 256, 0, stream>>>(q, k, v, g, out,
                                                          (float4*)d_ws);
        gla_pass2<CC><<<kBH, kD, 0, stream>>>((float*)d_ws);
        const int threads3 = kBH * kN * kD4;
        gla_pass3<CC><<<threads3 / 256, 256, 0, stream>>>(out,
                                                          (const float4*)d_ws);
    }
}